// Round 1
// baseline (5325.870 us; speedup 1.0000x reference)
//
#include <hip/hip_runtime.h>

// SpMM scatter baseline: out[row[e]] += val[e] * ego[col[e]], D=128 fp32.
// One wave (64 lanes) per edge: lane l handles elements [2l, 2l+1] as float2.
// Coalesced 512B gather per wave; 2 fp32 hardware atomics per lane.

constexpr int D = 128;

__global__ void __launch_bounds__(256)
spmm_scatter(const float* __restrict__ vals,
             const int* __restrict__ rows,
             const int* __restrict__ cols,
             const float* __restrict__ ego,
             float* __restrict__ out,
             int nnz) {
    int gid  = blockIdx.x * blockDim.x + threadIdx.x;
    int edge = gid >> 6;            // one wave per edge
    int lane = threadIdx.x & 63;
    if (edge >= nnz) return;

    // wave-uniform scalars (readfirstlane forces SGPR broadcast)
    int   r = __builtin_amdgcn_readfirstlane(rows[edge]);
    int   c = __builtin_amdgcn_readfirstlane(cols[edge]);
    float v = vals[edge];

    const float2* src = (const float2*)(ego + (size_t)c * D);
    float2 m = src[lane];

    float* dst = out + (size_t)r * D + 2 * lane;
    unsafeAtomicAdd(dst,     v * m.x);
    unsafeAtomicAdd(dst + 1, v * m.y);
}

extern "C" void kernel_launch(void* const* d_in, const int* in_sizes, int n_in,
                              void* d_out, int out_size, void* d_ws, size_t ws_size,
                              hipStream_t stream) {
    const float* ego  = (const float*)d_in[0];
    const float* vals = (const float*)d_in[1];
    const int*   rows = (const int*)d_in[2];
    const int*   cols = (const int*)d_in[3];
    float*       out  = (float*)d_out;
    int nnz = in_sizes[1];

    // harness poisons d_out to 0xAA before every launch — zero it ourselves
    hipMemsetAsync(d_out, 0, (size_t)out_size * sizeof(float), stream);

    // 4 waves (edges) per 256-thread block
    int blocks = (nnz + 3) / 4;
    spmm_scatter<<<blocks, 256, 0, stream>>>(vals, rows, cols, ego, out, nnz);
}

// Round 2
// 1386.207 us; speedup vs baseline: 3.8420x; 3.8420x over previous
//
#include <hip/hip_runtime.h>

// SpMM via on-device CSR build + deterministic gather (no fp atomics).
//   1. histogram: counts[r] = #edges with row==r          (int atomics, L2)
//   2. 3-kernel exclusive scan -> offsets, cursor
//   3. permute: spair[pos++] = (col, val) row-sorted      (int atomics, L2)
//   4. gather: one wave per row; acc in regs; one coalesced 512B write/row

constexpr int D = 128;
constexpr int SCAN_THREADS = 256;
constexpr int SCAN_ITEMS = 8;
constexpr int SCAN_TILE = SCAN_THREADS * SCAN_ITEMS;  // 2048

__global__ void histogram_k(const int* __restrict__ rows, int* __restrict__ counts, int nnz) {
    int i = blockIdx.x * blockDim.x + threadIdx.x;
    if (i < nnz) atomicAdd(&counts[rows[i]], 1);
}

__global__ void scan_a(const int* __restrict__ counts, int* __restrict__ tile_excl,
                       int* __restrict__ bsums, int n) {
    __shared__ int s[SCAN_THREADS];
    int tid = threadIdx.x;
    int base = blockIdx.x * SCAN_TILE + tid * SCAN_ITEMS;
    int v[SCAN_ITEMS];
    int tot = 0;
    for (int k = 0; k < SCAN_ITEMS; ++k) {
        int i = base + k;
        v[k] = (i < n) ? counts[i] : 0;
        tot += v[k];
    }
    s[tid] = tot;
    __syncthreads();
    for (int off = 1; off < SCAN_THREADS; off <<= 1) {
        int t = (tid >= off) ? s[tid - off] : 0;
        __syncthreads();
        s[tid] += t;
        __syncthreads();
    }
    int run = s[tid] - tot;  // exclusive
    for (int k = 0; k < SCAN_ITEMS; ++k) {
        int i = base + k;
        if (i < n) tile_excl[i] = run;
        run += v[k];
    }
    if (tid == SCAN_THREADS - 1) bsums[blockIdx.x] = s[tid];
}

__global__ void scan_b(int* __restrict__ bsums, int ntiles) {
    __shared__ int s[128];
    int tid = threadIdx.x;
    int v = (tid < ntiles) ? bsums[tid] : 0;
    s[tid] = v;
    __syncthreads();
    for (int off = 1; off < 128; off <<= 1) {
        int t = (tid >= off) ? s[tid - off] : 0;
        __syncthreads();
        s[tid] += t;
        __syncthreads();
    }
    if (tid < ntiles) bsums[tid] = s[tid] - v;  // exclusive
}

__global__ void scan_c(const int* __restrict__ tile_excl, const int* __restrict__ bsums,
                       int* __restrict__ offsets, int* __restrict__ cursor, int n, int nnz) {
    int i = blockIdx.x * blockDim.x + threadIdx.x;
    if (i < n) {
        int off = tile_excl[i] + bsums[i / SCAN_TILE];
        offsets[i] = off;
        cursor[i] = off;
    }
    if (i == 0) offsets[n] = nnz;
}

__global__ void permute_k(const int* __restrict__ rows, const int* __restrict__ cols,
                          const float* __restrict__ vals, int* __restrict__ cursor,
                          int2* __restrict__ spair, int nnz) {
    int i = blockIdx.x * blockDim.x + threadIdx.x;
    if (i >= nnz) return;
    int r = rows[i];
    int p = atomicAdd(&cursor[r], 1);
    spair[p] = make_int2(cols[i], __float_as_int(vals[i]));
}

__global__ void __launch_bounds__(256)
gather_k(const int* __restrict__ offsets, const int2* __restrict__ spair,
         const float* __restrict__ ego, float* __restrict__ out, int n) {
    int wid  = (blockIdx.x * blockDim.x + threadIdx.x) >> 6;  // one wave per row
    int lane = threadIdx.x & 63;
    if (wid >= n) return;
    int start = offsets[wid];
    int end   = offsets[wid + 1];
    float2 acc = {0.f, 0.f};
    for (int base = start; base < end; base += 64) {
        int j = base + lane;
        int2 cv = (j < end) ? spair[j] : make_int2(0, 0);  // coalesced 8B/lane
        int cnt = end - base;
        if (cnt > 64) cnt = 64;
        for (int k = 0; k < cnt; ++k) {
            int   c = __shfl(cv.x, k, 64);
            float v = __int_as_float(__shfl(cv.y, k, 64));
            float2 m = ((const float2*)(ego + (size_t)c * D))[lane];  // 512B/wave, L3-hit
            acc.x += v * m.x;
            acc.y += v * m.y;
        }
    }
    ((float2*)(out + (size_t)wid * D))[lane] = acc;  // coalesced, non-atomic
}

extern "C" void kernel_launch(void* const* d_in, const int* in_sizes, int n_in,
                              void* d_out, int out_size, void* d_ws, size_t ws_size,
                              hipStream_t stream) {
    const float* ego  = (const float*)d_in[0];
    const float* vals = (const float*)d_in[1];
    const int*   rows = (const int*)d_in[2];
    const int*   cols = (const int*)d_in[3];
    float*       out  = (float*)d_out;
    int nnz = in_sizes[1];
    int N   = out_size / D;  // 200000

    // workspace layout (ints), regions padded to 200704 (multiple of 2048)
    int* ws       = (int*)d_ws;
    int* counts   = ws;
    int* tilex    = ws + 200704;
    int* offsets  = ws + 401408;   // N+1
    int* cursor   = ws + 602112;
    int* bsums    = ws + 802816;   // 256
    int2* spair   = (int2*)(ws + 803072);  // 8B-aligned; NNZ int2 = 51.2 MB

    int ntiles = (N + SCAN_TILE - 1) / SCAN_TILE;  // 98 <= 128

    hipMemsetAsync(counts, 0, (size_t)N * sizeof(int), stream);
    histogram_k<<<(nnz + 255) / 256, 256, 0, stream>>>(rows, counts, nnz);
    scan_a<<<ntiles, SCAN_THREADS, 0, stream>>>(counts, tilex, bsums, N);
    scan_b<<<1, 128, 0, stream>>>(bsums, ntiles);
    scan_c<<<(N + 255) / 256, 256, 0, stream>>>(tilex, bsums, offsets, cursor, N, nnz);
    permute_k<<<(nnz + 255) / 256, 256, 0, stream>>>(rows, cols, vals, cursor, spair, nnz);
    gather_k<<<N / 4, 256, 0, stream>>>(offsets, spair, ego, out, N);  // 4 waves/block
}

// Round 3
// 926.291 us; speedup vs baseline: 5.7497x; 1.4965x over previous
//
#include <hip/hip_runtime.h>

// SpMM via two-level counting sort + deterministic gather.
//  1. coarse_count:   196-bucket histogram (row>>10), LDS-privatized
//  2. scan_buckets:   1-block scan -> bucket_base/cursor; offsets[N]=nnz
//  3. coarse_scatter: LDS multisplit per 8192-edge tile -> bucket-grouped
//                     (packed,val) pairs, coalesced ~336B runs
//  4. fine_permute:   one block per bucket; LDS 1024-row hist+scan; scatter
//                     confined to 262KB region (single CU -> L2-local line
//                     assembly); also writes CSR offsets
//  5. gather_k:       one wave per row, acc in regs, one 512B write per row

constexpr int D = 128;
constexpr int NB = 196;        // buckets of 1024 rows (200000 -> 196)
constexpr int TILE = 8192;
constexpr int THREADS = 256;

__global__ void __launch_bounds__(256)
coarse_count(const int* __restrict__ rows, int* __restrict__ bcnt, int nnz) {
    __shared__ int h[256];
    int tid = threadIdx.x;
    h[tid] = 0;
    __syncthreads();
    int base = blockIdx.x * TILE;
    int cnt = min(TILE, nnz - base);
    for (int i = tid; i < cnt; i += THREADS)
        atomicAdd(&h[rows[base + i] >> 10], 1);
    __syncthreads();
    if (h[tid]) atomicAdd(&bcnt[tid], h[tid]);
}

__global__ void __launch_bounds__(256)
scan_buckets(const int* __restrict__ bcnt, int* __restrict__ bbase,
             int* __restrict__ bcursor, int* __restrict__ offsets, int N, int nnz) {
    __shared__ int s[256];
    int tid = threadIdx.x;
    int v = (tid < NB) ? bcnt[tid] : 0;
    s[tid] = v;
    __syncthreads();
    for (int off = 1; off < 256; off <<= 1) {
        int t = (tid >= off) ? s[tid - off] : 0;
        __syncthreads();
        s[tid] += t;
        __syncthreads();
    }
    int ex = s[tid] - v;  // exclusive
    if (tid <= NB) bbase[tid] = ex;          // bbase[NB] = nnz
    if (tid < NB)  bcursor[tid] = ex;
    if (tid == 0)  offsets[N] = nnz;
}

__global__ void __launch_bounds__(256)
coarse_scatter(const int* __restrict__ rows, const int* __restrict__ cols,
               const float* __restrict__ vals, int* __restrict__ bcursor,
               int2* __restrict__ pairs, int nnz) {
    __shared__ int h[256], sc[256], cur[256], gb[256];
    __shared__ unsigned short src[TILE];
    int tid = threadIdx.x;
    h[tid] = 0;
    __syncthreads();
    int base = blockIdx.x * TILE;
    int cnt = min(TILE, nnz - base);
    for (int i = tid; i < cnt; i += THREADS)
        atomicAdd(&h[rows[base + i] >> 10], 1);
    __syncthreads();
    int v = h[tid];
    sc[tid] = v;
    __syncthreads();
    for (int off = 1; off < 256; off <<= 1) {
        int t = (tid >= off) ? sc[tid - off] : 0;
        __syncthreads();
        sc[tid] += t;
        __syncthreads();
    }
    int excl = sc[tid] - v;
    cur[tid] = excl;
    if (v) gb[tid] = atomicAdd(&bcursor[tid], v) - excl;  // gdst = gb[b] + slot
    __syncthreads();
    // place tile-local indices into bucket-sorted LDS order
    for (int i = tid; i < cnt; i += THREADS) {
        int b = rows[base + i] >> 10;
        int slot = atomicAdd(&cur[b], 1);
        src[slot] = (unsigned short)i;
    }
    __syncthreads();
    // emit bucket-grouped pairs: consecutive slots -> consecutive gdst
    for (int s_ = tid; s_ < cnt; s_ += THREADS) {
        int e = src[s_];
        int r = rows[base + e];
        int c = cols[base + e];
        float vv = vals[base + e];
        pairs[gb[r >> 10] + s_] = make_int2(((r & 1023) << 18) | c, __float_as_int(vv));
    }
}

__global__ void __launch_bounds__(1024)
fine_permute(const int* __restrict__ bbase, const int2* __restrict__ pairs,
             int2* __restrict__ fpairs, int* __restrict__ offsets, int N) {
    __shared__ int h[1024], s[1024], cur[1024];
    int b = blockIdx.x, tid = threadIdx.x;
    int base = bbase[b], end = bbase[b + 1], cnt = end - base;
    h[tid] = 0;
    __syncthreads();
    for (int i = tid; i < cnt; i += 1024)
        atomicAdd(&h[pairs[base + i].x >> 18], 1);
    __syncthreads();
    int v = h[tid];
    s[tid] = v;
    __syncthreads();
    for (int off = 1; off < 1024; off <<= 1) {
        int t = (tid >= off) ? s[tid - off] : 0;
        __syncthreads();
        s[tid] += t;
        __syncthreads();
    }
    int excl = s[tid] - v;
    cur[tid] = excl;
    int rg = (b << 10) + tid;
    if (rg < N) offsets[rg] = base + excl;   // CSR offsets for free
    __syncthreads();
    for (int i = tid; i < cnt; i += 1024) {
        int2 p = pairs[base + i];
        int pos = atomicAdd(&cur[p.x >> 18], 1);
        fpairs[base + pos] = p;   // 262KB window, single CU -> L2-local
    }
}

__global__ void __launch_bounds__(256)
gather_k(const int* __restrict__ offsets, const int2* __restrict__ pairs,
         const float* __restrict__ ego, float* __restrict__ out, int n) {
    int wid  = (blockIdx.x * blockDim.x + threadIdx.x) >> 6;
    int lane = threadIdx.x & 63;
    if (wid >= n) return;
    int start = offsets[wid];
    int end   = offsets[wid + 1];
    float2 acc = {0.f, 0.f};
    for (int bb = start; bb < end; bb += 64) {
        int j = bb + lane;
        int2 cv = (j < end) ? pairs[j] : make_int2(0, 0);
        int m_ = min(64, end - bb);
        for (int k = 0; k < m_; ++k) {
            int   c = __shfl(cv.x, k, 64) & 0x3FFFF;
            float v = __int_as_float(__shfl(cv.y, k, 64));
            float2 e = ((const float2*)(ego + (size_t)c * D))[lane];
            acc.x += v * e.x;
            acc.y += v * e.y;
        }
    }
    ((float2*)(out + (size_t)wid * D))[lane] = acc;
}

// insurance fallback (round-1 atomic scatter) if ws is too small
__global__ void __launch_bounds__(256)
spmm_scatter(const float* __restrict__ vals, const int* __restrict__ rows,
             const int* __restrict__ cols, const float* __restrict__ ego,
             float* __restrict__ out, int nnz) {
    int edge = (blockIdx.x * blockDim.x + threadIdx.x) >> 6;
    int lane = threadIdx.x & 63;
    if (edge >= nnz) return;
    int   r = __builtin_amdgcn_readfirstlane(rows[edge]);
    int   c = __builtin_amdgcn_readfirstlane(cols[edge]);
    float v = vals[edge];
    float2 m = ((const float2*)(ego + (size_t)c * D))[lane];
    float* dst = out + (size_t)r * D + 2 * lane;
    unsafeAtomicAdd(dst,     v * m.x);
    unsafeAtomicAdd(dst + 1, v * m.y);
}

extern "C" void kernel_launch(void* const* d_in, const int* in_sizes, int n_in,
                              void* d_out, int out_size, void* d_ws, size_t ws_size,
                              hipStream_t stream) {
    const float* ego  = (const float*)d_in[0];
    const float* vals = (const float*)d_in[1];
    const int*   rows = (const int*)d_in[2];
    const int*   cols = (const int*)d_in[3];
    float*       out  = (float*)d_out;
    int nnz = in_sizes[1];
    int N   = out_size / D;  // 200000

    size_t need = (size_t)(1024 + 200704) * 4 + (size_t)nnz * 16;
    if (ws_size < need) {
        hipMemsetAsync(d_out, 0, (size_t)out_size * sizeof(float), stream);
        spmm_scatter<<<(nnz + 3) / 4, 256, 0, stream>>>(vals, rows, cols, ego, out, nnz);
        return;
    }

    int* ws       = (int*)d_ws;
    int* bcnt     = ws;            // 256
    int* bbase    = ws + 256;      // 257 (pad 256)
    int* bcursor  = ws + 512;      // 256
    int* offsets  = ws + 1024;     // N+1, pad to 200704
    int2* pairs   = (int2*)(ws + 201728);
    int2* fpairs  = pairs + nnz;

    int ntiles = (nnz + TILE - 1) / TILE;  // 782

    hipMemsetAsync(bcnt, 0, 256 * sizeof(int), stream);
    coarse_count  <<<ntiles, 256, 0, stream>>>(rows, bcnt, nnz);
    scan_buckets  <<<1, 256, 0, stream>>>(bcnt, bbase, bcursor, offsets, N, nnz);
    coarse_scatter<<<ntiles, 256, 0, stream>>>(rows, cols, vals, bcursor, pairs, nnz);
    fine_permute  <<<NB, 1024, 0, stream>>>(bbase, pairs, fpairs, offsets, N);
    gather_k      <<<(N + 3) / 4, 256, 0, stream>>>(offsets, fpairs, ego, out, N);
}